// Round 9
// baseline (1082.983 us; speedup 1.0000x reference)
//
#include <hip/hip_runtime.h>
#include <hip/hip_bf16.h>

// SlotAttention: B=32, N=16384, D=64, S=7, H=128, 3 iterations.  TWO dispatches:
//   proj_kernel : self-sufficient (inline weight cvt, per-block q0, accumulator zeroing)
//                 LN->k,v (MFMA) + fused attn iter1 -> 128 plain partials/batch
//   iters_kernel: 1024 blocks x 256 thr (co-resident: launch_bounds(256,4) => >=4 blk/CU).
//                 Block g: batch b=g>>5, slice j=g&31 (512 rows).
//                 S1 (redundant partial-sum -> slots1 -> q2, no sync) -> A2 (atomicAdd
//                 transport, R1-proven) -> relaxed ctr + sleep-poll (32/batch) -> S2
//                 (redundant, wide) -> A3 -> j==0: S3 -> out.
//                 NO fences (R5), NO narrow finisher tails (R6/R7), NO narrow grids (R8).

#define B_ 32
#define N_ 16384
#define D_ 64
#define S_ 7

typedef __bf16 bf16x8 __attribute__((ext_vector_type(8)));
typedef float floatx4 __attribute__((ext_vector_type(4)));

__device__ __forceinline__ unsigned int f2bfu(float f) {
  __hip_bfloat16 h = __float2bfloat16(f);
  return (unsigned int)__builtin_bit_cast(unsigned short, h);
}
__device__ __forceinline__ unsigned int pack2bf(float lo, float hi) {
  return f2bfu(lo) | (f2bfu(hi) << 16);
}
__device__ __forceinline__ float atomic_read(float* p) { return atomicAdd(p, 0.0f); }

// ---------------- proj + fused attention iteration 1 (R4 body) ----------------
__global__ __launch_bounds__(256, 4) void proj_kernel(
    const float* __restrict__ x,
    const float* __restrict__ lng, const float* __restrict__ lnb,
    const float* __restrict__ Wk, const float* __restrict__ Wv,
    const float* __restrict__ mu, const float* __restrict__ lsig,
    const float* __restrict__ nslots,
    const float* __restrict__ ln_s_g, const float* __restrict__ ln_s_b,
    const float* __restrict__ Wq,
    unsigned short* __restrict__ kb, unsigned short* __restrict__ vt,
    float* __restrict__ Wp, float* __restrict__ Cp,
    float* __restrict__ Wacc, int* __restrict__ ctrs)
{
  __shared__ __align__(16) unsigned char smemA[18432];
  __shared__ __align__(16) unsigned short s_vo[64 * 136];   // 17408 B
  __shared__ __align__(16) unsigned short s_qb[1024];       // 2048 B
  __shared__ float s_cred[4][8];
  unsigned short* s_xn = (unsigned short*)smemA;            // [128][64] xor-swizzled
  unsigned short* s_ko = (unsigned short*)smemA;            // [128][72]
  unsigned short* s_at = (unsigned short*)smemA;            // [4][16][40]
  float* s_red = (float*)(smemA + 5120);                    // [4][448]

  const int t = threadIdx.x, lane = t & 63, w = t >> 6;
  const int R0 = blockIdx.x * 128;
  const int bb = R0 >> 14;
  const int tile = blockIdx.x;

  // zero iter accumulators (29184 floats = Wacc[2*14336]+Cacc[2*256]) + 64 ctr ints
  if (tile < 114) Wacc[tile * 256 + t] = 0.f;
  else if (tile == 114 && t < 64) ctrs[t] = 0;

  // q0 for this block's batch: slots0 -> LN -> @Wq^T*scale -> s_qb (bf16, rows>=7 zero)
  *(uint2*)&s_qb[t * 4] = make_uint2(0, 0);
  {
    float* s_sl = (float*)s_vo;     // scratch (s_vo dead until v-part)
    float* s_tp = s_sl + 448;
    for (int o = t; o < 448; o += 256) {
      int d = o & 63;
      s_sl[o] = mu[d] + expf(lsig[d]) * nslots[bb * 448 + o];
    }
    __syncthreads();
    for (int ss = 0; ss < 2; ++ss) {
      int srow = ss * 4 + w;
      if (srow < 7) {
        float xv = s_sl[srow * 64 + lane];
        float s1 = xv, s2 = xv * xv;
#pragma unroll
        for (int mm = 1; mm < 64; mm <<= 1) {
          s1 += __shfl_xor(s1, mm);
          s2 += __shfl_xor(s2, mm);
        }
        float mean = s1 * 0.015625f;
        float var = s2 * 0.015625f - mean * mean;
        float rs = rsqrtf(var + 1e-5f);
        s_tp[w * 64 + lane] = (xv - mean) * rs * ln_s_g[lane] + ln_s_b[lane];
      }
      __syncthreads();
      if (srow < 7) {
        float acc = 0.f;
        const float4* wr = (const float4*)(Wq + lane * 64);
        const float4* xr = (const float4*)(s_tp + w * 64);
#pragma unroll
        for (int i = 0; i < 16; ++i) {
          float4 a = wr[i], xx = xr[i];
          acc += a.x * xx.x + a.y * xx.y + a.z * xx.z + a.w * xx.w;
        }
        s_qb[srow * 64 + lane] = (unsigned short)f2bfu(acc * 0.125f);
      }
      __syncthreads();
    }
  }

  // LayerNorm of x: 4 lanes per row, 16 f32 each -> s_xn (swizzled bf16)
  const int ql = t & 3;
  float4 g4[4], b4[4];
#pragma unroll
  for (int j = 0; j < 4; ++j) {
    g4[j] = *(const float4*)&lng[ql * 16 + j * 4];
    b4[j] = *(const float4*)&lnb[ql * 16 + j * 4];
  }
#pragma unroll
  for (int half = 0; half < 2; ++half) {
    int r = half * 64 + (t >> 2);
    const float4* xp = (const float4*)&x[(size_t)(R0 + r) * 64 + ql * 16];
    float4 xv[4];
#pragma unroll
    for (int j = 0; j < 4; ++j) xv[j] = xp[j];
    float s1 = 0.f, s2 = 0.f;
#pragma unroll
    for (int j = 0; j < 4; ++j) {
      s1 += xv[j].x + xv[j].y + xv[j].z + xv[j].w;
      s2 += xv[j].x * xv[j].x + xv[j].y * xv[j].y + xv[j].z * xv[j].z + xv[j].w * xv[j].w;
    }
    s1 += __shfl_xor(s1, 1); s2 += __shfl_xor(s2, 1);
    s1 += __shfl_xor(s1, 2); s2 += __shfl_xor(s2, 2);
    float mean = s1 * 0.015625f;
    float var = s2 * 0.015625f - mean * mean;
    float rs = rsqrtf(var + 1e-5f);
    float y[16];
#pragma unroll
    for (int j = 0; j < 4; ++j) {
      y[j * 4 + 0] = (xv[j].x - mean) * rs * g4[j].x + b4[j].x;
      y[j * 4 + 1] = (xv[j].y - mean) * rs * g4[j].y + b4[j].y;
      y[j * 4 + 2] = (xv[j].z - mean) * rs * g4[j].z + b4[j].z;
      y[j * 4 + 3] = (xv[j].w - mean) * rs * g4[j].w + b4[j].w;
    }
#pragma unroll
    for (int h = 0; h < 2; ++h) {
      uint4 p;
      p.x = pack2bf(y[h * 8 + 0], y[h * 8 + 1]);
      p.y = pack2bf(y[h * 8 + 2], y[h * 8 + 3]);
      p.z = pack2bf(y[h * 8 + 4], y[h * 8 + 5]);
      p.w = pack2bf(y[h * 8 + 6], y[h * 8 + 7]);
      int c = ql * 2 + h;
      int sc = c ^ (r & 7);
      *(uint4*)&s_xn[r * 64 + sc * 8] = p;
    }
  }
  __syncthreads();

  const int m16 = lane & 15, quad = lane >> 4;
  bf16x8 bq0 = *(const bf16x8*)&s_qb[m16 * 64 + quad * 8];
  bf16x8 bq1 = *(const bf16x8*)&s_qb[m16 * 64 + 32 + quad * 8];

  bf16x8 bf[2][2];
#pragma unroll
  for (int rt = 0; rt < 2; ++rt) {
    int xr = (w * 2 + rt) * 16 + m16;
#pragma unroll
    for (int kk = 0; kk < 2; ++kk)
      bf[rt][kk] = *(const bf16x8*)&s_xn[xr * 64 + (((kk * 4 + quad) ^ (xr & 7)) * 8)];
  }
  // weight fragments: inline f32 -> bf16 conversion (L2-broadcast)
  bf16x8 wkf[4][2], wvf[4][2];
#pragma unroll
  for (int ft = 0; ft < 4; ++ft)
#pragma unroll
    for (int kk = 0; kk < 2; ++kk) {
      const float* wp = Wk + (ft * 16 + m16) * 64 + kk * 32 + quad * 8;
      float4 a = *(const float4*)wp, b2 = *(const float4*)(wp + 4);
      uint4 pk;
      pk.x = pack2bf(a.x, a.y);  pk.y = pack2bf(a.z, a.w);
      pk.z = pack2bf(b2.x, b2.y); pk.w = pack2bf(b2.z, b2.w);
      wkf[ft][kk] = __builtin_bit_cast(bf16x8, pk);
      const float* vp = Wv + (ft * 16 + m16) * 64 + kk * 32 + quad * 8;
      float4 c = *(const float4*)vp, d2 = *(const float4*)(vp + 4);
      uint4 pv;
      pv.x = pack2bf(c.x, c.y);  pv.y = pack2bf(c.z, c.w);
      pv.z = pack2bf(d2.x, d2.y); pv.w = pack2bf(d2.z, d2.w);
      wvf[ft][kk] = __builtin_bit_cast(bf16x8, pv);
    }
  __syncthreads();

  // k-part
#pragma unroll
  for (int ft = 0; ft < 4; ++ft)
#pragma unroll
    for (int rt = 0; rt < 2; ++rt) {
      floatx4 acc = (floatx4){0.f, 0.f, 0.f, 0.f};
      acc = __builtin_amdgcn_mfma_f32_16x16x32_bf16(wkf[ft][0], bf[rt][0], acc, 0, 0, 0);
      acc = __builtin_amdgcn_mfma_f32_16x16x32_bf16(wkf[ft][1], bf[rt][1], acc, 0, 0, 0);
      int n_l = (w * 2 + rt) * 16 + m16;
      uint2 p;
      p.x = pack2bf(acc[0], acc[1]);
      p.y = pack2bf(acc[2], acc[3]);
      *(uint2*)&s_ko[n_l * 72 + ft * 16 + quad * 4] = p;
    }
  __syncthreads();

  // v-part -> s_vo
#pragma unroll
  for (int ft = 0; ft < 4; ++ft)
#pragma unroll
    for (int rt = 0; rt < 2; ++rt) {
      floatx4 acc = (floatx4){0.f, 0.f, 0.f, 0.f};
      acc = __builtin_amdgcn_mfma_f32_16x16x32_bf16(bf[rt][0], wvf[ft][0], acc, 0, 0, 0);
      acc = __builtin_amdgcn_mfma_f32_16x16x32_bf16(bf[rt][1], wvf[ft][1], acc, 0, 0, 0);
      int n_l = (w * 2 + rt) * 16 + quad * 4;
      int d0 = ft * 16 + m16;
      uint2 p;
      p.x = pack2bf(acc[0], acc[1]);
      p.y = pack2bf(acc[2], acc[3]);
      *(uint2*)&s_vo[d0 * 136 + n_l] = p;
    }
  bf16x8 ak[2][2];
#pragma unroll
  for (int rt = 0; rt < 2; ++rt) {
    int row = (w * 2 + rt) * 16 + m16;
    ak[rt][0] = *(const bf16x8*)&s_ko[row * 72 + quad * 8];
    ak[rt][1] = *(const bf16x8*)&s_ko[row * 72 + 32 + quad * 8];
  }
#pragma unroll
  for (int p = 0; p < 4; ++p) {
    int ii = (p * 256 + t) * 8;
    int n_l = ii >> 6, dl = ii & 63;
    uint4 v4 = *(const uint4*)&s_ko[n_l * 72 + dl];
    *(uint4*)&kb[(size_t)(R0 + n_l) * 64 + dl] = v4;
  }
  __syncthreads();   // region A: s_ko dead -> s_at + s_red

  // fused attention iter 1
  float cl = 0.f;
#pragma unroll
  for (int rt = 0; rt < 2; ++rt) {
    floatx4 c = (floatx4){0.f, 0.f, 0.f, 0.f};
    c = __builtin_amdgcn_mfma_f32_16x16x32_bf16(ak[rt][0], bq0, c, 0, 0, 0);
    c = __builtin_amdgcn_mfma_f32_16x16x32_bf16(ak[rt][1], bq1, c, 0, 0, 0);
    float atv[4];
#pragma unroll
    for (int rg = 0; rg < 4; ++rg) {
      float e = (m16 < 7) ? __expf(c[rg]) : 0.f;
      float sm = e;
      sm += __shfl_xor(sm, 1);
      sm += __shfl_xor(sm, 2);
      sm += __shfl_xor(sm, 4);
      float a = e * __builtin_amdgcn_rcpf(sm) + 1e-8f;
      atv[rg] = a;
      cl += a;
    }
    if (m16 < 7) {
      uint2 p;
      p.x = pack2bf(atv[0], atv[1]);
      p.y = pack2bf(atv[2], atv[3]);
      *(uint2*)&s_at[w * 640 + m16 * 40 + rt * 16 + quad * 4] = p;
    }
  }
  asm volatile("s_waitcnt lgkmcnt(0)" ::: "memory");
  bf16x8 af = *(const bf16x8*)&s_at[w * 640 + m16 * 40 + quad * 8];
  floatx4 acc2[4];
#pragma unroll
  for (int dt = 0; dt < 4; ++dt) acc2[dt] = (floatx4){0.f, 0.f, 0.f, 0.f};
#pragma unroll
  for (int dt = 0; dt < 4; ++dt) {
    bf16x8 bv = *(const bf16x8*)&s_vo[(dt * 16 + m16) * 136 + w * 32 + quad * 8];
    acc2[dt] = __builtin_amdgcn_mfma_f32_16x16x32_bf16(af, bv, acc2[dt], 0, 0, 0);
  }
  if (quad < 2) {
#pragma unroll
    for (int dt = 0; dt < 4; ++dt)
#pragma unroll
      for (int rg = 0; rg < 4; ++rg) {
        int s = quad * 4 + rg;
        if (s < 7) s_red[w * 448 + s * 64 + dt * 16 + m16] = acc2[dt][rg];
      }
  }
  cl += __shfl_xor(cl, 16);
  cl += __shfl_xor(cl, 32);
  if (m16 < 7 && quad == 0) s_cred[w][m16] = cl;
  __syncthreads();

  // epilogue: plain per-block partials + tiled vt store
  for (int o = t; o < 448; o += 256) {
    float v = s_red[o] + s_red[448 + o] + s_red[896 + o] + s_red[1344 + o];
    Wp[(size_t)tile * 448 + o] = v;
  }
  if (t < 7) {
    float c = s_cred[0][t] + s_cred[1][t] + s_cred[2][t] + s_cred[3][t];
    Cp[(size_t)tile * 8 + t] = c;
  }
#pragma unroll
  for (int p = 0; p < 4; ++p) {
    int ii = (p * 256 + t) * 8;
    uint4 v4 = *(const uint4*)&s_vo[(ii >> 7) * 136 + (ii & 127)];
    *(uint4*)&vt[(size_t)tile * 8192 + ii] = v4;
  }
}

// ---------------- slot core (256 threads): s_upd -> GRU -> MLP -> slots (+out/+q) ----------------
__device__ void slot_core(
    int t, int lane, int w,
    float* s_upd, float* s_gi, float* s_slot, const float* s_h0,
    unsigned short* s_qb,
    const float* __restrict__ w_ih, const float* __restrict__ w_hh,
    const float* __restrict__ b_ih, const float* __restrict__ b_hh,
    const float* __restrict__ ln_m_g, const float* __restrict__ ln_m_b,
    const float* __restrict__ w1, const float* __restrict__ b1,
    const float* __restrict__ w2, const float* __restrict__ b2,
    const float* __restrict__ ln_s_g, const float* __restrict__ ln_s_b,
    const float* __restrict__ Wq,
    float* __restrict__ outp, int flags)
{
  __syncthreads();   // s_upd ready
  for (int o = t; o < 1344; o += 256) {
    int s = o / 192, j = o - s * 192;
    float acc = b_ih[j];
    const float4* wr = (const float4*)(w_ih + j * 64);
    const float4* ur = (const float4*)(s_upd + s * 64);
#pragma unroll
    for (int i = 0; i < 16; ++i) {
      float4 a = wr[i], u = ur[i];
      acc += a.x * u.x + a.y * u.y + a.z * u.z + a.w * u.w;
    }
    s_gi[o] = acc;
  }
  __syncthreads();
  if (w == 0) {
    float h = s_h0[lane];
    const float bhr = b_hh[lane], bhz = b_hh[64 + lane], bhn = b_hh[128 + lane];
    const float4* wr4 = (const float4*)(w_hh + lane * 64);
    const float4* wz4 = (const float4*)(w_hh + (64 + lane) * 64);
    const float4* wn4 = (const float4*)(w_hh + (128 + lane) * 64);
    for (int s = 0; s < 7; ++s) {
      float ar = bhr, az = bhz, an = bhn;
#pragma unroll
      for (int i = 0; i < 16; ++i) {
        float4 a = wr4[i], zz = wz4[i], c = wn4[i];
        float h0 = __shfl(h, i * 4 + 0), h1 = __shfl(h, i * 4 + 1);
        float h2 = __shfl(h, i * 4 + 2), h3 = __shfl(h, i * 4 + 3);
        ar += a.x * h0 + a.y * h1 + a.z * h2 + a.w * h3;
        az += zz.x * h0 + zz.y * h1 + zz.z * h2 + zz.w * h3;
        an += c.x * h0 + c.y * h1 + c.z * h2 + c.w * h3;
      }
      float ir = s_gi[s * 192 + lane], iz = s_gi[s * 192 + 64 + lane], inn = s_gi[s * 192 + 128 + lane];
      float r = 1.f / (1.f + __expf(-(ir + ar)));
      float z = 1.f / (1.f + __expf(-(iz + az)));
      float n = tanhf(inn + r * an);
      h = (1.f - z) * n + z * h;
      s_slot[s * 64 + lane] = h;
    }
  }
  __syncthreads();
  float* s_sn = s_gi;
  float* s_hid = s_gi + 448;
#pragma unroll
  for (int ss = 0; ss < 2; ++ss) {
    int srow = ss * 4 + w;
    if (srow < 7) {
      float xv = s_slot[srow * 64 + lane];
      float s1 = xv, s2 = xv * xv;
#pragma unroll
      for (int mm = 1; mm < 64; mm <<= 1) {
        s1 += __shfl_xor(s1, mm);
        s2 += __shfl_xor(s2, mm);
      }
      float mean = s1 * 0.015625f;
      float var = s2 * 0.015625f - mean * mean;
      float rs = rsqrtf(var + 1e-5f);
      s_sn[srow * 64 + lane] = (xv - mean) * rs * ln_m_g[lane] + ln_m_b[lane];
    }
  }
  __syncthreads();
  for (int o = t; o < 896; o += 256) {
    int s = o >> 7, hh = o & 127;
    float acc = b1[hh];
    const float4* wr = (const float4*)(w1 + hh * 64);
    const float4* xr = (const float4*)(s_sn + s * 64);
#pragma unroll
    for (int i = 0; i < 16; ++i) {
      float4 a = wr[i], xx = xr[i];
      acc += a.x * xx.x + a.y * xx.y + a.z * xx.z + a.w * xx.w;
    }
    s_hid[o] = fmaxf(acc, 0.f);
  }
  __syncthreads();
  for (int o = t; o < 448; o += 256) {
    int s = o >> 6, d = o & 63;
    float acc = b2[d];
    const float4* wr = (const float4*)(w2 + d * 128);
    const float4* hr = (const float4*)(s_hid + s * 128);
#pragma unroll
    for (int i = 0; i < 32; ++i) {
      float4 a = wr[i], hv = hr[i];
      acc += a.x * hv.x + a.y * hv.y + a.z * hv.z + a.w * hv.w;
    }
    float val = s_slot[o] + acc;
    s_slot[o] = val;
    if (flags & 1) outp[o] = val;
  }
  __syncthreads();
  if (flags & 2) {
#pragma unroll
    for (int ss = 0; ss < 2; ++ss) {
      int srow = ss * 4 + w;
      if (srow < 7) {
        float xv = s_slot[srow * 64 + lane];
        float s1 = xv, s2 = xv * xv;
#pragma unroll
        for (int mm = 1; mm < 64; mm <<= 1) {
          s1 += __shfl_xor(s1, mm);
          s2 += __shfl_xor(s2, mm);
        }
        float mean = s1 * 0.015625f;
        float var = s2 * 0.015625f - mean * mean;
        float rs = rsqrtf(var + 1e-5f);
        s_upd[srow * 64 + lane] = (xv - mean) * rs * ln_s_g[lane] + ln_s_b[lane];
      }
    }
    __syncthreads();
#pragma unroll
    for (int ss = 0; ss < 2; ++ss) {
      int srow = ss * 4 + w;
      if (srow < 7) {
        float acc = 0.f;
        const float4* wr = (const float4*)(Wq + lane * 64);
        const float4* xr = (const float4*)(s_upd + srow * 64);
#pragma unroll
        for (int i = 0; i < 16; ++i) {
          float4 a = wr[i], xx = xr[i];
          acc += a.x * xx.x + a.y * xx.y + a.z * xx.z + a.w * xx.w;
        }
        s_qb[srow * 64 + lane] = (unsigned short)f2bfu(acc * 0.125f);
      }
    }
    __syncthreads();
  }
}

// ---------------- iters: 1024 blocks x 256 thr; batch b = g>>5, slice j = g&31 ----------------
__global__ __launch_bounds__(256, 4) void iters_kernel(
    const unsigned short* __restrict__ kb, const unsigned short* __restrict__ vt,
    const float* __restrict__ Wp, const float* __restrict__ Cp,
    float* __restrict__ Wacc, float* __restrict__ Cacc, int* __restrict__ ctrs,
    const float* __restrict__ mu, const float* __restrict__ lsig,
    const float* __restrict__ nh,
    const float* __restrict__ w_ih, const float* __restrict__ w_hh,
    const float* __restrict__ b_ih, const float* __restrict__ b_hh,
    const float* __restrict__ ln_m_g, const float* __restrict__ ln_m_b,
    const float* __restrict__ w1, const float* __restrict__ b1,
    const float* __restrict__ w2, const float* __restrict__ b2,
    const float* __restrict__ ln_s_g, const float* __restrict__ ln_s_b,
    const float* __restrict__ Wq,
    float* __restrict__ out)
{
  __shared__ __align__(16) unsigned short s_qb[1024];       // q bf16 [16][64], rows>=7 zero
  __shared__ __align__(16) unsigned char smemB[16384];      // attn: s_at 9216 + s_red 7168
  __shared__ float s_cred[4][8];                            // overlay (slot): s_upd/s_gi/s_slot/s_cs
  __shared__ float s_h0[64];

  const int g = blockIdx.x, b = g >> 5, j = g & 31;
  const int t = threadIdx.x, lane = t & 63, w = t >> 6;
  const int m16 = lane & 15, quad = lane >> 4;

  unsigned short* s_at = (unsigned short*)smemB;            // [4][1152] shorts
  float* s_red  = (float*)(smemB + 9216);                   // [4][448]
  float* s_upd  = (float*)smemB;                            // 448  (overlay)
  float* s_gi   = s_upd + 448;                              // 1344
  float* s_slot = s_upd + 1792;                             // 448
  float* s_cs   = s_upd + 2240;                             // 8

  *(uint2*)&s_qb[t * 4] = make_uint2(0, 0);
  if (t < 64) s_h0[t] = mu[t] + expf(lsig[t]) * nh[b * 64 + t];

  // ---- S1: redundant slot update 1 from proj's 128 partials (plain loads) ----
  if (t < 7) {
    float cs = 0.f;
#pragma unroll 8
    for (int p = 0; p < 128; ++p) cs += Cp[((size_t)b * 128 + p) * 8 + t];
    s_cs[t] = cs;
  }
  __syncthreads();
  for (int o = t; o < 448; o += 256) {
    float acc = 0.f;
#pragma unroll 8
    for (int p = 0; p < 128; ++p) acc += Wp[((size_t)b * 128 + p) * 448 + o];
    s_upd[o] = acc / s_cs[o >> 6];
  }
  slot_core(t, lane, w, s_upd, s_gi, s_slot, s_h0, s_qb,
            w_ih, w_hh, b_ih, b_hh, ln_m_g, ln_m_b, w1, b1, w2, b2,
            ln_s_g, ln_s_b, Wq, nullptr, /*flags=*/2);

  // ---- iterations 2,3 ----
  const unsigned short* kbA = kb + ((size_t)b * N_ + j * 512 + w * 128) * 64;
  for (int it = 0; it < 2; ++it) {
    bf16x8 bq0 = *(const bf16x8*)&s_qb[m16 * 64 + quad * 8];
    bf16x8 bq1 = *(const bf16x8*)&s_qb[m16 * 64 + 32 + quad * 8];

    floatx4 acc[4];
#pragma unroll
    for (int dt = 0; dt < 4; ++dt) acc[dt] = (floatx4){0.f, 0.f, 0.f, 0.f};
    float cl = 0.f;

#pragma unroll
    for (int c = 0; c < 2; ++c) {
      bf16x8 ak0[4], ak1[4];
#pragma unroll
      for (int nt = 0; nt < 4; ++nt) {
        const unsigned short* kr = kbA + (size_t)(c * 64 + nt * 16 + m16) * 64;
        ak0[nt] = *(const bf16x8*)&kr[quad * 8];
        ak1[nt] = *(const bf16x8*)&kr[32 + quad * 8];
      }
#pragma unroll
      for (int nt = 0; nt < 4; ++nt) {
        floatx4 cc = (floatx4){0.f, 0.f, 0.f, 0.f};
        cc = __builtin_amdgcn_mfma_f32_16x16x32_bf16(ak0[nt], bq0, cc, 0, 0, 0);
        cc = __builtin_amdgcn_mfma_f32_16x16x32_bf16(ak1[nt], bq1, cc, 0, 0, 0);
        float atv[4];
#pragma unroll
        for (int rg = 0; rg < 4; ++rg) {
          float e = (m16 < 7) ? __expf(cc[rg]) : 0.f;
          float sm = e;
          sm += __shfl_xor(sm, 1);
          sm += __shfl_xor(sm, 2);
          sm += __shfl_xor(sm, 4);
          float a = e * __builtin_amdgcn_rcpf(sm) + 1e-8f;
          atv[rg] = a;
          cl += a;
        }
        if (m16 < 7) {
          uint2 p;
          p.x = pack2bf(atv[0], atv[1]);
          p.y = pack2bf(atv[2], atv[3]);
          *(uint2*)&s_at[w * 1152 + m16 * 72 + nt * 16 + quad * 4] = p;
        }
      }
      asm volatile("s_waitcnt lgkmcnt(0)" ::: "memory");
      bf16x8 af0 = *(const bf16x8*)&s_at[w * 1152 + m16 * 72 + quad * 8];
      bf16x8 af1 = *(const bf16x8*)&s_at[w * 1152 + m16 * 72 + 32 + quad * 8];
      const int R = j * 512 + w * 128 + c * 64;
      const unsigned short* vtB = vt + ((size_t)b * 128 + (R >> 7)) * 8192 + (R & 127);
#pragma unroll
      for (int ch = 0; ch < 2; ++ch) {
        bf16x8 bv[4];
#pragma unroll
        for (int dt = 0; dt < 4; ++dt)
          bv[dt] = *(const bf16x8*)&vtB[(dt * 16 + m16) * 128 + ch * 32 + quad * 8];
        bf16x8 af = (ch == 0) ? af0 : af1;
#pragma unroll
        for (int dt = 0; dt < 4; ++dt)
          acc[dt] = __builtin_amdgcn_mfma_f32_16x16x32_bf16(af, bv[dt], acc[dt], 0, 0, 0);
      }
    }

    if (quad < 2) {
#pragma unroll
      for (int dt = 0; dt < 4; ++dt)
#pragma unroll
        for (int rg = 0; rg < 4; ++rg) {
          int s = quad * 4 + rg;
          if (s < 7) s_red[w * 448 + s * 64 + dt * 16 + m16] = acc[dt][rg];
        }
    }
    cl += __shfl_xor(cl, 16);
    cl += __shfl_xor(cl, 32);
    if (m16 < 7 && quad == 0) s_cred[w][m16] = cl;
    __syncthreads();

    float* Wa = Wacc + it * 14336;
    float* Ca = Cacc + it * 256;
    int* ct = ctrs + it * 32;
    for (int o = t; o < 448; o += 256) {
      float v = s_red[o] + s_red[448 + o] + s_red[896 + o] + s_red[1344 + o];
      atomicAdd(&Wa[b * 448 + o], v);
    }
    if (t < 7) {
      float c = s_cred[0][t] + s_cred[1][t] + s_cred[2][t] + s_cred[3][t];
      atomicAdd(&Ca[b * 8 + t], c);
    }
    __syncthreads();   // drains this block's data atomics (vmcnt)
    if (t == 0)
      __hip_atomic_fetch_add(ct + b, 1, __ATOMIC_RELAXED, __HIP_MEMORY_SCOPE_AGENT);
    __syncthreads();   // ctr add drained
    if (it == 1 && j != 0) return;   // final slot update: only slice 0 proceeds
    if (t == 0) {
      while (__hip_atomic_load(ct + b, __ATOMIC_RELAXED, __HIP_MEMORY_SCOPE_AGENT) < 32)
        __builtin_amdgcn_s_sleep(32);
    }
    __syncthreads();

    // S(it+2): all remaining blocks redundantly (atomic reads at coherent point)
    if (t < 7) s_cs[t] = atomic_read(&Ca[b * 8 + t]);
    __syncthreads();
    for (int o = t; o < 448; o += 256)
      s_upd[o] = atomic_read(&Wa[b * 448 + o]) / s_cs[o >> 6];
    slot_core(t, lane, w, s_upd, s_gi, s_slot, s_h0, s_qb,
              w_ih, w_hh, b_ih, b_hh, ln_m_g, ln_m_b, w1, b1, w2, b2,
              ln_s_g, ln_s_b, Wq, out + b * 448,
              /*flags=*/(it == 1) ? 1 : 2);
  }
}

extern "C" void kernel_launch(void* const* d_in, const int* in_sizes, int n_in,
                              void* d_out, int out_size, void* d_ws, size_t ws_size,
                              hipStream_t stream)
{
  (void)in_sizes; (void)n_in; (void)out_size; (void)ws_size;
  const float* x      = (const float*)d_in[0];
  const float* ln_in_g = (const float*)d_in[1];
  const float* ln_in_b = (const float*)d_in[2];
  const float* ln_s_g  = (const float*)d_in[3];
  const float* ln_s_b  = (const float*)d_in[4];
  const float* ln_m_g  = (const float*)d_in[5];
  const float* ln_m_b  = (const float*)d_in[6];
  const float* Wq = (const float*)d_in[7];
  const float* Wk = (const float*)d_in[8];
  const float* Wv = (const float*)d_in[9];
  const float* mu = (const float*)d_in[10];
  const float* lsig = (const float*)d_in[11];
  const float* w_ih = (const float*)d_in[12];
  const float* w_hh = (const float*)d_in[13];
  const float* b_ih = (const float*)d_in[14];
  const float* b_hh = (const float*)d_in[15];
  const float* w1 = (const float*)d_in[16];
  const float* b1 = (const float*)d_in[17];
  const float* w2 = (const float*)d_in[18];
  const float* b2 = (const float*)d_in[19];
  const float* nslots = (const float*)d_in[20];
  const float* nh = (const float*)d_in[21];

  unsigned short* kb = (unsigned short*)d_ws;                // k[b][n][d] bf16
  unsigned short* vt = kb + (size_t)B_ * N_ * D_;            // vt tiled [b*128+chunk][64][128]
  float* fb   = (float*)(vt + (size_t)B_ * N_ * D_);
  float* Wp   = fb;                  // 4096*448 proj partials
  float* Cp   = Wp + 1835008;        // 4096*8
  float* Wacc = Cp + 32768;          // 2*14336 (iters 2,3)
  float* Cacc = Wacc + 28672;        // 2*256   (contiguous with Wacc for zeroing)
  int*   ctrs = (int*)(Cacc + 512);  // 2*32
  float* out = (float*)d_out;

  proj_kernel<<<4096, 256, 0, stream>>>(x, ln_in_g, ln_in_b, Wk, Wv,
                                        mu, lsig, nslots, ln_s_g, ln_s_b, Wq,
                                        kb, vt, Wp, Cp, Wacc, ctrs);
  iters_kernel<<<1024, 256, 0, stream>>>(kb, vt, Wp, Cp, Wacc, Cacc, ctrs,
                                         mu, lsig, nh,
                                         w_ih, w_hh, b_ih, b_hh, ln_m_g, ln_m_b,
                                         w1, b1, w2, b2, ln_s_g, ln_s_b, Wq, out);
}

// Round 10
// 521.138 us; speedup vs baseline: 2.0781x; 2.0781x over previous
//
#include <hip/hip_runtime.h>
#include <hip/hip_bf16.h>

// SlotAttention: B=32, N=16384, D=64, S=7, H=128, 3 iterations.
// 6 dispatches, multi-dispatch only (R5-R9: ALL in-kernel cross-block sync forms
// cost 350-1500us on gfx950 -- handoff happens at kernel boundaries ONLY):
//   proj_kernel : self-sufficient (inline weight cvt, per-block q0) LN->k,v (MFMA)
//                 + fused attn iter1 -> 128 partials/batch, vt stored TILED
//   slot_kernel : partial-sum -> 1-wave L2-direct GRU -> MLP -> q/out (256 thr)
//   attn_kernel : 8-wave/1024-n blocks, grid(16,32), tiled-vt streaming -> 16 partials
//   (slot, attn, slot) x ...

#define B_ 32
#define N_ 16384
#define D_ 64
#define S_ 7

typedef __bf16 bf16x8 __attribute__((ext_vector_type(8)));
typedef float floatx4 __attribute__((ext_vector_type(4)));

__device__ __forceinline__ unsigned int f2bfu(float f) {
  __hip_bfloat16 h = __float2bfloat16(f);
  return (unsigned int)__builtin_bit_cast(unsigned short, h);
}
__device__ __forceinline__ unsigned int pack2bf(float lo, float hi) {
  return f2bfu(lo) | (f2bfu(hi) << 16);
}

// ---------------- proj + fused attention iteration 1 (R4 body, self-sufficient) ----------------
__global__ __launch_bounds__(256, 4) void proj_kernel(
    const float* __restrict__ x,
    const float* __restrict__ lng, const float* __restrict__ lnb,
    const float* __restrict__ Wk, const float* __restrict__ Wv,
    const float* __restrict__ mu, const float* __restrict__ lsig,
    const float* __restrict__ nslots,
    const float* __restrict__ ln_s_g, const float* __restrict__ ln_s_b,
    const float* __restrict__ Wq,
    unsigned short* __restrict__ kb, unsigned short* __restrict__ vt,
    float* __restrict__ Wp, float* __restrict__ Cp)
{
  __shared__ __align__(16) unsigned char smemA[18432];
  __shared__ __align__(16) unsigned short s_vo[64 * 136];   // 17408 B
  __shared__ __align__(16) unsigned short s_qb[1024];       // 2048 B
  __shared__ float s_cred[4][8];
  unsigned short* s_xn = (unsigned short*)smemA;            // [128][64] xor-swizzled
  unsigned short* s_ko = (unsigned short*)smemA;            // [128][72]
  unsigned short* s_at = (unsigned short*)smemA;            // [4][16][40]
  float* s_red = (float*)(smemA + 5120);                    // [4][448]

  const int t = threadIdx.x, lane = t & 63, w = t >> 6;
  const int R0 = blockIdx.x * 128;
  const int bb = R0 >> 14;
  const int tile = blockIdx.x;

  // q0 for this block's batch: slots0 -> LN -> @Wq^T*scale -> s_qb (bf16, rows>=7 zero)
  *(uint2*)&s_qb[t * 4] = make_uint2(0, 0);
  {
    float* s_sl = (float*)s_vo;     // scratch (s_vo dead until v-part)
    float* s_tp = s_sl + 448;
    for (int o = t; o < 448; o += 256) {
      int d = o & 63;
      s_sl[o] = mu[d] + expf(lsig[d]) * nslots[bb * 448 + o];
    }
    __syncthreads();
    for (int ss = 0; ss < 2; ++ss) {
      int srow = ss * 4 + w;
      if (srow < 7) {
        float xv = s_sl[srow * 64 + lane];
        float s1 = xv, s2 = xv * xv;
#pragma unroll
        for (int mm = 1; mm < 64; mm <<= 1) {
          s1 += __shfl_xor(s1, mm);
          s2 += __shfl_xor(s2, mm);
        }
        float mean = s1 * 0.015625f;
        float var = s2 * 0.015625f - mean * mean;
        float rs = rsqrtf(var + 1e-5f);
        s_tp[w * 64 + lane] = (xv - mean) * rs * ln_s_g[lane] + ln_s_b[lane];
      }
      __syncthreads();
      if (srow < 7) {
        float acc = 0.f;
        const float4* wr = (const float4*)(Wq + lane * 64);
        const float4* xr = (const float4*)(s_tp + w * 64);
#pragma unroll
        for (int i = 0; i < 16; ++i) {
          float4 a = wr[i], xx = xr[i];
          acc += a.x * xx.x + a.y * xx.y + a.z * xx.z + a.w * xx.w;
        }
        s_qb[srow * 64 + lane] = (unsigned short)f2bfu(acc * 0.125f);
      }
      __syncthreads();
    }
  }

  // LayerNorm of x -> s_xn (swizzled bf16)
  const int ql = t & 3;
  float4 g4[4], b4[4];
#pragma unroll
  for (int j = 0; j < 4; ++j) {
    g4[j] = *(const float4*)&lng[ql * 16 + j * 4];
    b4[j] = *(const float4*)&lnb[ql * 16 + j * 4];
  }
#pragma unroll
  for (int half = 0; half < 2; ++half) {
    int r = half * 64 + (t >> 2);
    const float4* xp = (const float4*)&x[(size_t)(R0 + r) * 64 + ql * 16];
    float4 xv[4];
#pragma unroll
    for (int j = 0; j < 4; ++j) xv[j] = xp[j];
    float s1 = 0.f, s2 = 0.f;
#pragma unroll
    for (int j = 0; j < 4; ++j) {
      s1 += xv[j].x + xv[j].y + xv[j].z + xv[j].w;
      s2 += xv[j].x * xv[j].x + xv[j].y * xv[j].y + xv[j].z * xv[j].z + xv[j].w * xv[j].w;
    }
    s1 += __shfl_xor(s1, 1); s2 += __shfl_xor(s2, 1);
    s1 += __shfl_xor(s1, 2); s2 += __shfl_xor(s2, 2);
    float mean = s1 * 0.015625f;
    float var = s2 * 0.015625f - mean * mean;
    float rs = rsqrtf(var + 1e-5f);
    float y[16];
#pragma unroll
    for (int j = 0; j < 4; ++j) {
      y[j * 4 + 0] = (xv[j].x - mean) * rs * g4[j].x + b4[j].x;
      y[j * 4 + 1] = (xv[j].y - mean) * rs * g4[j].y + b4[j].y;
      y[j * 4 + 2] = (xv[j].z - mean) * rs * g4[j].z + b4[j].z;
      y[j * 4 + 3] = (xv[j].w - mean) * rs * g4[j].w + b4[j].w;
    }
#pragma unroll
    for (int h = 0; h < 2; ++h) {
      uint4 p;
      p.x = pack2bf(y[h * 8 + 0], y[h * 8 + 1]);
      p.y = pack2bf(y[h * 8 + 2], y[h * 8 + 3]);
      p.z = pack2bf(y[h * 8 + 4], y[h * 8 + 5]);
      p.w = pack2bf(y[h * 8 + 6], y[h * 8 + 7]);
      int c = ql * 2 + h;
      int sc = c ^ (r & 7);
      *(uint4*)&s_xn[r * 64 + sc * 8] = p;
    }
  }
  __syncthreads();

  const int m16 = lane & 15, quad = lane >> 4;
  bf16x8 bq0 = *(const bf16x8*)&s_qb[m16 * 64 + quad * 8];
  bf16x8 bq1 = *(const bf16x8*)&s_qb[m16 * 64 + 32 + quad * 8];

  bf16x8 bf[2][2];
#pragma unroll
  for (int rt = 0; rt < 2; ++rt) {
    int xr = (w * 2 + rt) * 16 + m16;
#pragma unroll
    for (int kk = 0; kk < 2; ++kk)
      bf[rt][kk] = *(const bf16x8*)&s_xn[xr * 64 + (((kk * 4 + quad) ^ (xr & 7)) * 8)];
  }
  // weight fragments: inline f32 -> bf16 conversion (L2-broadcast)
  bf16x8 wkf[4][2], wvf[4][2];
#pragma unroll
  for (int ft = 0; ft < 4; ++ft)
#pragma unroll
    for (int kk = 0; kk < 2; ++kk) {
      const float* wp = Wk + (ft * 16 + m16) * 64 + kk * 32 + quad * 8;
      float4 a = *(const float4*)wp, b2 = *(const float4*)(wp + 4);
      uint4 pk;
      pk.x = pack2bf(a.x, a.y);  pk.y = pack2bf(a.z, a.w);
      pk.z = pack2bf(b2.x, b2.y); pk.w = pack2bf(b2.z, b2.w);
      wkf[ft][kk] = __builtin_bit_cast(bf16x8, pk);
      const float* vp = Wv + (ft * 16 + m16) * 64 + kk * 32 + quad * 8;
      float4 c = *(const float4*)vp, d2 = *(const float4*)(vp + 4);
      uint4 pv;
      pv.x = pack2bf(c.x, c.y);  pv.y = pack2bf(c.z, c.w);
      pv.z = pack2bf(d2.x, d2.y); pv.w = pack2bf(d2.z, d2.w);
      wvf[ft][kk] = __builtin_bit_cast(bf16x8, pv);
    }
  __syncthreads();

  // k-part
#pragma unroll
  for (int ft = 0; ft < 4; ++ft)
#pragma unroll
    for (int rt = 0; rt < 2; ++rt) {
      floatx4 acc = (floatx4){0.f, 0.f, 0.f, 0.f};
      acc = __builtin_amdgcn_mfma_f32_16x16x32_bf16(wkf[ft][0], bf[rt][0], acc, 0, 0, 0);
      acc = __builtin_amdgcn_mfma_f32_16x16x32_bf16(wkf[ft][1], bf[rt][1], acc, 0, 0, 0);
      int n_l = (w * 2 + rt) * 16 + m16;
      uint2 p;
      p.x = pack2bf(acc[0], acc[1]);
      p.y = pack2bf(acc[2], acc[3]);
      *(uint2*)&s_ko[n_l * 72 + ft * 16 + quad * 4] = p;
    }
  __syncthreads();

  // v-part -> s_vo
#pragma unroll
  for (int ft = 0; ft < 4; ++ft)
#pragma unroll
    for (int rt = 0; rt < 2; ++rt) {
      floatx4 acc = (floatx4){0.f, 0.f, 0.f, 0.f};
      acc = __builtin_amdgcn_mfma_f32_16x16x32_bf16(bf[rt][0], wvf[ft][0], acc, 0, 0, 0);
      acc = __builtin_amdgcn_mfma_f32_16x16x32_bf16(bf[rt][1], wvf[ft][1], acc, 0, 0, 0);
      int n_l = (w * 2 + rt) * 16 + quad * 4;
      int d0 = ft * 16 + m16;
      uint2 p;
      p.x = pack2bf(acc[0], acc[1]);
      p.y = pack2bf(acc[2], acc[3]);
      *(uint2*)&s_vo[d0 * 136 + n_l] = p;
    }
  bf16x8 ak[2][2];
#pragma unroll
  for (int rt = 0; rt < 2; ++rt) {
    int row = (w * 2 + rt) * 16 + m16;
    ak[rt][0] = *(const bf16x8*)&s_ko[row * 72 + quad * 8];
    ak[rt][1] = *(const bf16x8*)&s_ko[row * 72 + 32 + quad * 8];
  }
#pragma unroll
  for (int p = 0; p < 4; ++p) {
    int ii = (p * 256 + t) * 8;
    int n_l = ii >> 6, dl = ii & 63;
    uint4 v4 = *(const uint4*)&s_ko[n_l * 72 + dl];
    *(uint4*)&kb[(size_t)(R0 + n_l) * 64 + dl] = v4;
  }
  __syncthreads();   // region A: s_ko dead -> s_at + s_red

  // fused attention iter 1
  float cl = 0.f;
#pragma unroll
  for (int rt = 0; rt < 2; ++rt) {
    floatx4 c = (floatx4){0.f, 0.f, 0.f, 0.f};
    c = __builtin_amdgcn_mfma_f32_16x16x32_bf16(ak[rt][0], bq0, c, 0, 0, 0);
    c = __builtin_amdgcn_mfma_f32_16x16x32_bf16(ak[rt][1], bq1, c, 0, 0, 0);
    float atv[4];
#pragma unroll
    for (int rg = 0; rg < 4; ++rg) {
      float e = (m16 < 7) ? __expf(c[rg]) : 0.f;
      float sm = e;
      sm += __shfl_xor(sm, 1);
      sm += __shfl_xor(sm, 2);
      sm += __shfl_xor(sm, 4);
      float a = e * __builtin_amdgcn_rcpf(sm) + 1e-8f;
      atv[rg] = a;
      cl += a;
    }
    if (m16 < 7) {
      uint2 p;
      p.x = pack2bf(atv[0], atv[1]);
      p.y = pack2bf(atv[2], atv[3]);
      *(uint2*)&s_at[w * 640 + m16 * 40 + rt * 16 + quad * 4] = p;
    }
  }
  asm volatile("s_waitcnt lgkmcnt(0)" ::: "memory");
  bf16x8 af = *(const bf16x8*)&s_at[w * 640 + m16 * 40 + quad * 8];
  floatx4 acc2[4];
#pragma unroll
  for (int dt = 0; dt < 4; ++dt) acc2[dt] = (floatx4){0.f, 0.f, 0.f, 0.f};
#pragma unroll
  for (int dt = 0; dt < 4; ++dt) {
    bf16x8 bv = *(const bf16x8*)&s_vo[(dt * 16 + m16) * 136 + w * 32 + quad * 8];
    acc2[dt] = __builtin_amdgcn_mfma_f32_16x16x32_bf16(af, bv, acc2[dt], 0, 0, 0);
  }
  if (quad < 2) {
#pragma unroll
    for (int dt = 0; dt < 4; ++dt)
#pragma unroll
      for (int rg = 0; rg < 4; ++rg) {
        int s = quad * 4 + rg;
        if (s < 7) s_red[w * 448 + s * 64 + dt * 16 + m16] = acc2[dt][rg];
      }
  }
  cl += __shfl_xor(cl, 16);
  cl += __shfl_xor(cl, 32);
  if (m16 < 7 && quad == 0) s_cred[w][m16] = cl;
  __syncthreads();

  // epilogue: plain per-block partials + tiled vt store
  for (int o = t; o < 448; o += 256) {
    float v = s_red[o] + s_red[448 + o] + s_red[896 + o] + s_red[1344 + o];
    Wp[(size_t)tile * 448 + o] = v;
  }
  if (t < 7) {
    float c = s_cred[0][t] + s_cred[1][t] + s_cred[2][t] + s_cred[3][t];
    Cp[(size_t)tile * 8 + t] = c;
  }
#pragma unroll
  for (int p = 0; p < 4; ++p) {
    int ii = (p * 256 + t) * 8;
    uint4 v4 = *(const uint4*)&s_vo[(ii >> 7) * 136 + (ii & 127)];
    *(uint4*)&vt[(size_t)tile * 8192 + ii] = v4;
  }
}

// ---------------- slot update (256 thr; 1-wave L2-direct GRU) ----------------
// flags: bit0 = write out, bit1 = write next q (f32, global)
__global__ __launch_bounds__(256) void slot_kernel(
    const float* __restrict__ Wp, const float* __restrict__ Cp, int npart,
    const float* __restrict__ mu, const float* __restrict__ lsig,
    const float* __restrict__ nh,
    const float* __restrict__ w_ih, const float* __restrict__ w_hh,
    const float* __restrict__ b_ih, const float* __restrict__ b_hh,
    const float* __restrict__ ln_m_g, const float* __restrict__ ln_m_b,
    const float* __restrict__ w1, const float* __restrict__ b1,
    const float* __restrict__ w2, const float* __restrict__ b2,
    const float* __restrict__ ln_s_g, const float* __restrict__ ln_s_b,
    const float* __restrict__ Wq,
    float* __restrict__ qbuf, float* __restrict__ out, int flags)
{
  __shared__ float s_upd[448];
  __shared__ float s_gi[1344];
  __shared__ float s_slot[448];
  __shared__ float s_cs[8];
  __shared__ float s_h0[64];
  const int b = blockIdx.x, t = threadIdx.x, lane = t & 63, w = t >> 6;

  if (t < 64) s_h0[t] = mu[t] + expf(lsig[t]) * nh[b * 64 + t];
  if (t < 7) {
    float cs = 0.f;
#pragma unroll 8
    for (int p = 0; p < npart; ++p) cs += Cp[((size_t)b * npart + p) * 8 + t];
    s_cs[t] = cs;
  }
  __syncthreads();
  for (int o = t; o < 448; o += 256) {
    float acc = 0.f;
#pragma unroll 8
    for (int p = 0; p < npart; ++p) acc += Wp[((size_t)b * npart + p) * 448 + o];
    s_upd[o] = acc / s_cs[o >> 6];
  }
  __syncthreads();
  // gi = updates @ w_ih^T + b_ih
  for (int o = t; o < 1344; o += 256) {
    int s = o / 192, j = o - s * 192;
    float acc = b_ih[j];
    const float4* wr = (const float4*)(w_ih + j * 64);
    const float4* ur = (const float4*)(s_upd + s * 64);
#pragma unroll
    for (int i = 0; i < 16; ++i) {
      float4 a = wr[i], u = ur[i];
      acc += a.x * u.x + a.y * u.y + a.z * u.z + a.w * u.w;
    }
    s_gi[o] = acc;
  }
  __syncthreads();
  // GRU: wave 0, h in registers, w_hh rows from L2, no barriers inside.
  if (w == 0) {
    float h = s_h0[lane];
    const float bhr = b_hh[lane], bhz = b_hh[64 + lane], bhn = b_hh[128 + lane];
    const float4* wr4 = (const float4*)(w_hh + lane * 64);
    const float4* wz4 = (const float4*)(w_hh + (64 + lane) * 64);
    const float4* wn4 = (const float4*)(w_hh + (128 + lane) * 64);
    for (int s = 0; s < 7; ++s) {
      float ar = bhr, az = bhz, an = bhn;
#pragma unroll
      for (int i = 0; i < 16; ++i) {
        float4 a = wr4[i], zz = wz4[i], c = wn4[i];
        float h0 = __shfl(h, i * 4 + 0), h1 = __shfl(h, i * 4 + 1);
        float h2 = __shfl(h, i * 4 + 2), h3 = __shfl(h, i * 4 + 3);
        ar += a.x * h0 + a.y * h1 + a.z * h2 + a.w * h3;
        az += zz.x * h0 + zz.y * h1 + zz.z * h2 + zz.w * h3;
        an += c.x * h0 + c.y * h1 + c.z * h2 + c.w * h3;
      }
      float ir = s_gi[s * 192 + lane], iz = s_gi[s * 192 + 64 + lane], inn = s_gi[s * 192 + 128 + lane];
      float r = 1.f / (1.f + __expf(-(ir + ar)));
      float z = 1.f / (1.f + __expf(-(iz + az)));
      float n = tanhf(inn + r * an);
      h = (1.f - z) * n + z * h;
      s_slot[s * 64 + lane] = h;
    }
  }
  __syncthreads();
  // MLP with residual (s_sn/s_hid overlay s_gi)
  float* s_sn = s_gi;
  float* s_hid = s_gi + 448;
#pragma unroll
  for (int ss = 0; ss < 2; ++ss) {
    int srow = ss * 4 + w;
    if (srow < 7) {
      float xv = s_slot[srow * 64 + lane];
      float s1 = xv, s2 = xv * xv;
#pragma unroll
      for (int mm = 1; mm < 64; mm <<= 1) {
        s1 += __shfl_xor(s1, mm);
        s2 += __shfl_xor(s2, mm);
      }
      float mean = s1 * 0.015625f;
      float var = s2 * 0.015625f - mean * mean;
      float rs = rsqrtf(var + 1e-5f);
      s_sn[srow * 64 + lane] = (xv - mean) * rs * ln_m_g[lane] + ln_m_b[lane];
    }
  }
  __syncthreads();
  for (int o = t; o < 896; o += 256) {
    int s = o >> 7, hh = o & 127;
    float acc = b1[hh];
    const float4* wr = (const float4*)(w1 + hh * 64);
    const float4* xr = (const float4*)(s_sn + s * 64);
#pragma unroll
    for (int i = 0; i < 16; ++i) {
      float4 a = wr[i], xx = xr[i];
      acc += a.x * xx.x + a.y * xx.y + a.z * xx.z + a.w * xx.w;
    }
    s_hid[o] = fmaxf(acc, 0.f);
  }
  __syncthreads();
  for (int o = t; o < 448; o += 256) {
    int s = o >> 6, d = o & 63;
    float acc = b2[d];
    const float4* wr = (const float4*)(w2 + d * 128);
    const float4* hr = (const float4*)(s_hid + s * 128);
#pragma unroll
    for (int i = 0; i < 32; ++i) {
      float4 a = wr[i], hv = hr[i];
      acc += a.x * hv.x + a.y * hv.y + a.z * hv.z + a.w * hv.w;
    }
    float val = s_slot[o] + acc;
    s_slot[o] = val;
    if (flags & 1) out[b * 448 + o] = val;
  }
  __syncthreads();
  if (flags & 2) {
    // next q = LN(slots; ln_slots) @ Wq^T * scale -> qbuf (f32)
#pragma unroll
    for (int ss = 0; ss < 2; ++ss) {
      int srow = ss * 4 + w;
      if (srow < 7) {
        float xv = s_slot[srow * 64 + lane];
        float s1 = xv, s2 = xv * xv;
#pragma unroll
        for (int mm = 1; mm < 64; mm <<= 1) {
          s1 += __shfl_xor(s1, mm);
          s2 += __shfl_xor(s2, mm);
        }
        float mean = s1 * 0.015625f;
        float var = s2 * 0.015625f - mean * mean;
        float rs = rsqrtf(var + 1e-5f);
        s_upd[srow * 64 + lane] = (xv - mean) * rs * ln_s_g[lane] + ln_s_b[lane];
      }
    }
    __syncthreads();
#pragma unroll
    for (int ss = 0; ss < 2; ++ss) {
      int srow = ss * 4 + w;
      if (srow < 7) {
        float acc = 0.f;
        const float4* wr = (const float4*)(Wq + lane * 64);
        const float4* xr = (const float4*)(s_upd + srow * 64);
#pragma unroll
        for (int i = 0; i < 16; ++i) {
          float4 a = wr[i], xx = xr[i];
          acc += a.x * xx.x + a.y * xx.y + a.z * xx.z + a.w * xx.w;
        }
        qbuf[b * 448 + srow * 64 + lane] = acc * 0.125f;
      }
    }
  }
}

// ---------------- attention (iters 2,3): grid(16,32), 512 thr, 8 waves x 128 n ----------------
__global__ __launch_bounds__(512, 2) void attn_kernel(
    const unsigned short* __restrict__ kb, const unsigned short* __restrict__ vt,
    const float* __restrict__ qbuf,
    float* __restrict__ Wp, float* __restrict__ Cp)
{
  __shared__ __align__(16) unsigned short s_qb[1024];       // q bf16 [16][64], rows>=7 zero
  __shared__ __align__(16) unsigned short s_at[8][1152];    // per-wave attn bf16 [16][72]
  __shared__ __align__(16) float s_red[8][448];
  __shared__ float s_cred[8][8];

  const int b = blockIdx.y, bx = blockIdx.x;
  const int t = threadIdx.x, lane = t & 63, w = t >> 6;
  const int m16 = lane & 15, quad = lane >> 4;

  if (t < 256) {
    int i0 = t * 4;
    int s = i0 >> 6, d0 = i0 & 63;
    float f0 = 0.f, f1 = 0.f, f2 = 0.f, f3 = 0.f;
    if (s < 7) {
      const float* qp = qbuf + b * 448 + s * 64 + d0;
      f0 = qp[0]; f1 = qp[1]; f2 = qp[2]; f3 = qp[3];
    }
    uint2 p;
    p.x = pack2bf(f0, f1);
    p.y = pack2bf(f2, f3);
    *(uint2*)&s_qb[i0] = p;
  }
  __syncthreads();

  bf16x8 bq0 = *(const bf16x8*)&s_qb[m16 * 64 + quad * 8];
  bf16x8 bq1 = *(const bf16x8*)&s_qb[m16 * 64 + 32 + quad * 8];

  const unsigned short* kbA = kb + ((size_t)b * N_ + bx * 1024 + w * 128) * 64;
  floatx4 acc[4];
#pragma unroll
  for (int dt = 0; dt < 4; ++dt) acc[dt] = (floatx4){0.f, 0.f, 0.f, 0.f};
  float cl = 0.f;

#pragma unroll
  for (int c = 0; c < 2; ++c) {
    bf16x8 ak0[4], ak1[4];
#pragma unroll
    for (int nt = 0; nt < 4; ++nt) {
      const unsigned short* kr = kbA + (size_t)(c * 64 + nt * 16 + m16) * 64;
      ak0[nt] = *(const bf16x8*)&kr[quad * 8];
      ak1[nt] = *(const bf16x8*)&kr[32 + quad * 8];
    }
#pragma unroll
    for (int nt = 0; nt < 4; ++nt) {
      floatx4 cc = (floatx4){0.f, 0.f, 0.f, 0.f};
      cc = __builtin_amdgcn_mfma_f32_16x16x32_bf16(ak0[nt], bq0, cc, 0, 0, 0);
      cc = __builtin_amdgcn_mfma_f32_16x16x32_bf16(ak1[nt], bq1, cc, 0, 0, 0);
      float atv[4];
#pragma unroll
      for (int rg = 0; rg < 4; ++rg) {
        float e = (m16 < 7) ? __expf(cc[rg]) : 0.f;
        float sm = e;
        sm += __shfl_xor(sm, 1);
        sm += __shfl_xor(sm, 2);
        sm += __shfl_xor(sm, 4);
        float a = e * __builtin_amdgcn_rcpf(sm) + 1e-8f;
        atv[rg] = a;
        cl += a;
      }
      if (m16 < 7) {
        uint2 p;
        p.x = pack2bf(atv[0], atv[1]);
        p.y = pack2bf(atv[2], atv[3]);
        *(uint2*)&s_at[w][m16 * 72 + nt * 16 + quad * 4] = p;
      }
    }
    // wave-private LDS: drain writes before frag reads
    asm volatile("s_waitcnt lgkmcnt(0)" ::: "memory");
    bf16x8 af0 = *(const bf16x8*)&s_at[w][m16 * 72 + quad * 8];
    bf16x8 af1 = *(const bf16x8*)&s_at[w][m16 * 72 + 32 + quad * 8];
    const int R = bx * 1024 + w * 128 + c * 64;
    const unsigned short* vtB = vt + ((size_t)b * 128 + (R >> 7)) * 8192 + (R & 127);
#pragma unroll
    for (int ch = 0; ch < 2; ++ch) {
      bf16x8 bv[4];
#pragma unroll
      for (int dt = 0; dt < 4; ++dt)
        bv[dt] = *(const bf16x8*)&vtB[(dt * 16 + m16) * 128 + ch * 32 + quad * 8];
      bf16x8 af = (ch == 0) ? af0 : af1;
#pragma unroll
      for (int dt = 0; dt < 4; ++dt)
        acc[dt] = __builtin_amdgcn_mfma_f32_16x16x32_bf16(af, bv[dt], acc[dt], 0, 0, 0);
    }
  }

  if (quad < 2) {
#pragma unroll
    for (int dt = 0; dt < 4; ++dt)
#pragma unroll
      for (int rg = 0; rg < 4; ++rg) {
        int s = quad * 4 + rg;
        if (s < 7) s_red[w][s * 64 + dt * 16 + m16] = acc[dt][rg];
      }
  }
  cl += __shfl_xor(cl, 16);
  cl += __shfl_xor(cl, 32);
  if (m16 < 7 && quad == 0) s_cred[w][m16] = cl;
  __syncthreads();

  if (t < 448) {
    float v = 0.f;
#pragma unroll
    for (int wv = 0; wv < 8; ++wv) v += s_red[wv][t];
    Wp[((size_t)b * 16 + bx) * 448 + t] = v;
  } else if (t < 455) {
    int s = t - 448;
    float c = 0.f;
#pragma unroll
    for (int wv = 0; wv < 8; ++wv) c += s_cred[wv][s];
    Cp[((size_t)b * 16 + bx) * 8 + s] = c;
  }
}

extern "C" void kernel_launch(void* const* d_in, const int* in_sizes, int n_in,
                              void* d_out, int out_size, void* d_ws, size_t ws_size,
                              hipStream_t stream)
{
  (void)in_sizes; (void)n_in; (void)out_size; (void)ws_size;
  const float* x      = (const float*)d_in[0];
  const float* ln_in_g = (const float*)d_in[1];
  const float* ln_in_b = (const float*)d_in[2];
  const float* ln_s_g  = (const float*)d_in[3];
  const float* ln_s_b  = (const float*)d_in[4];
  const float* ln_m_g  = (const float*)d_in[5];
  const float* ln_m_b  = (const float*)d_in[6];
  const float* Wq = (const float*)d_in[7];
  const float* Wk = (const float*)d_in[8];
  const float* Wv = (const float*)d_in[9];
  const float* mu = (const float*)d_in[10];
  const float* lsig = (const float*)d_in[11];
  const float* w_ih = (const float*)d_in[12];
  const float* w_hh = (const float*)d_in[13];
  const float* b_ih = (const float*)d_in[14];
  const float* b_hh = (const float*)d_in[15];
  const float* w1 = (const float*)d_in[16];
  const float* b1 = (const float*)d_in[17];
  const float* w2 = (const float*)d_in[18];
  const float* b2 = (const float*)d_in[19];
  const float* nslots = (const float*)d_in[20];
  const float* nh = (const float*)d_in[21];

  unsigned short* kb = (unsigned short*)d_ws;                // k[b][n][d] bf16
  unsigned short* vt = kb + (size_t)B_ * N_ * D_;            // vt tiled [b*128+chunk][64][128]
  float* fb   = (float*)(vt + (size_t)B_ * N_ * D_);
  float* Wp_p = fb;                  // 4096*448 proj partials
  float* Cp_p = Wp_p + 1835008;      // 4096*8
  float* Wp_a = Cp_p + 32768;        // 512*448 attn partials
  float* Cp_a = Wp_a + 229376;       // 512*8
  float* qbuf = Cp_a + 4096;         // 32*448
  float* out = (float*)d_out;

  // iter 1 fused into proj (q0 computed per-block)
  proj_kernel<<<4096, 256, 0, stream>>>(x, ln_in_g, ln_in_b, Wk, Wv,
                                        mu, lsig, nslots, ln_s_g, ln_s_b, Wq,
                                        kb, vt, Wp_p, Cp_p);
  slot_kernel<<<32, 256, 0, stream>>>(Wp_p, Cp_p, 128, mu, lsig, nh,
                                      w_ih, w_hh, b_ih, b_hh, ln_m_g, ln_m_b,
                                      w1, b1, w2, b2, ln_s_g, ln_s_b, Wq,
                                      qbuf, out, /*flags=*/2);
  attn_kernel<<<dim3(16, 32), 512, 0, stream>>>(kb, vt, qbuf, Wp_a, Cp_a);
  slot_kernel<<<32, 256, 0, stream>>>(Wp_a, Cp_a, 16, mu, lsig, nh,
                                      w_ih, w_hh, b_ih, b_hh, ln_m_g, ln_m_b,
                                      w1, b1, w2, b2, ln_s_g, ln_s_b, Wq,
                                      qbuf, out, /*flags=*/2);
  attn_kernel<<<dim3(16, 32), 512, 0, stream>>>(kb, vt, qbuf, Wp_a, Cp_a);
  slot_kernel<<<32, 256, 0, stream>>>(Wp_a, Cp_a, 16, mu, lsig, nh,
                                      w_ih, w_hh, b_ih, b_hh, ln_m_g, ln_m_b,
                                      w1, b1, w2, b2, ln_s_g, ln_s_b, Wq,
                                      qbuf, out, /*flags=*/1);
}